// Round 15
// baseline (13.836 us; speedup 1.0000x reference)
//
#include <hip/hip_runtime.h>
#include <hip/hip_fp16.h>
#include <math.h>

// Problem constants: B=1024, IN_DIM=4096, OUT_DIM=4096, FAN_IN=8
#define BDIM 1024
#define IN_DIM 4096
#define OUT_DIM 4096
#define FAN_IN 8
#define NT 1024
#define TILE_B 4
#define NTILES (BDIM / TILE_B)   // 256
#define HALF_OUT (OUT_DIM / 2)   // 2048
#define OPT (HALF_OUT / NT)      // 2 outputs per thread

#define LOG2E 1.442695040888963f
#define LN2   0.6931471805599453f

__device__ __forceinline__ float fast_exp(float v) {
    return exp2f(v * LOG2E);   // v_exp_f32
}

union H2U { __half2 h; unsigned int u; };

__global__ __launch_bounds__(NT, 8) void WeightedThresholdGate_53085795778563_kernel(
    const float* __restrict__ x,      // [B, IN_DIM]
    const int*   __restrict__ idx,    // [OUT_DIM, FAN_IN]
    const float* __restrict__ w,      // [OUT_DIM, FAN_IN]
    const float* __restrict__ theta,  // [OUT_DIM]
    const float* __restrict__ s_raw,  // [OUT_DIM]
    float*       __restrict__ out)    // [B, OUT_DIM]
{
    // R14 structure (best measured: 13.77us) + packed-f16 gather FMA.
    // Blocks (T) and (T+256) own batch rows 4T..4T+3; each gathers half the
    // outputs; pair shares bid%8 -> same XCD L2 for the duplicated stage.
    __shared__ __align__(8) uint2 xT[IN_DIM];   // 32 KiB, f16 transposed tile

    const int t    = threadIdx.x;
    const int tile = blockIdx.x & (NTILES - 1);
    const int half = blockIdx.x >> 8;
    const int b0   = tile * TILE_B;

    const float* __restrict__ xr0 = x + (size_t)(b0 + 0) * IN_DIM;
    const float* __restrict__ xr1 = x + (size_t)(b0 + 1) * IN_DIM;
    const float* __restrict__ xr2 = x + (size_t)(b0 + 2) * IN_DIM;
    const float* __restrict__ xr3 = x + (size_t)(b0 + 3) * IN_DIM;

    // Stage: scalar coalesced loads, cvt_pkrtz f16 pack, lane-contiguous
    // ds_write_b64 (conflict-free).
#pragma unroll
    for (int k = 0; k < IN_DIM / NT; ++k) {
        const int j = t + k * NT;
        H2U lo, hi;
        lo.h = __floats2half2_rn(xr0[j], xr1[j]);   // rows 0,1
        hi.h = __floats2half2_rn(xr2[j], xr3[j]);   // rows 2,3
        xT[j] = make_uint2(lo.u, hi.u);
    }
    __syncthreads();

#pragma unroll
    for (int i = 0; i < OPT; ++i) {
        const int o = half * HALF_OUT + t + i * NT;   // strided: coalesced idx/w/out

        const int4*   ip = reinterpret_cast<const int4*>(idx + (size_t)o * FAN_IN);
        const float4* wp = reinterpret_cast<const float4*>(w  + (size_t)o * FAN_IN);
        const int4   i0 = ip[0], i1 = ip[1];
        const float4 w0 = wp[0], w1 = wp[1];

        // Packed-f16 accumulators: lanes {row01, row23}; 3 VALU per gather
        // (1 cvt + 2 v_pk_fma_f16) vs 6 in the scalar-f32 version.
        __half2 acc01 = __float2half2_rn(0.0f);
        __half2 acc23 = __float2half2_rn(0.0f);

#define GATHER(J, WF)                                              \
        {                                                          \
            const uint2 gg = xT[(J)];                              \
            H2U glo, ghi; glo.u = gg.x; ghi.u = gg.y;              \
            const __half2 wh = __float2half2_rn((WF));             \
            acc01 = __hfma2(glo.h, wh, acc01);                     \
            acc23 = __hfma2(ghi.h, wh, acc23);                     \
        }

        GATHER(i0.x, w0.x); GATHER(i0.y, w0.y);
        GATHER(i0.z, w0.z); GATHER(i0.w, w0.w);
        GATHER(i1.x, w1.x); GATHER(i1.y, w1.y);
        GATHER(i1.z, w1.z); GATHER(i1.w, w1.w);
#undef GATHER

        const float2 f01 = __half22float2(acc01);
        const float2 f23 = __half22float2(acc23);

        const float th = theta[o];
        const float sr = s_raw[o];
        // softplus(sr)+1e-6, stable; log via v_log_f32: log1p(u)=log2(1+u)*ln2
        const float sp = fmaxf(sr, 0.0f) + LN2 * log2f(1.0f + fast_exp(-fabsf(sr)));
        const float s  = sp + 1e-6f;

        const float g0 = 1.0f / (1.0f + fast_exp(-s * (f01.x - th)));
        const float g1 = 1.0f / (1.0f + fast_exp(-s * (f01.y - th)));
        const float g2 = 1.0f / (1.0f + fast_exp(-s * (f23.x - th)));
        const float g3 = 1.0f / (1.0f + fast_exp(-s * (f23.y - th)));

        // Streamed output: nontemporal, coalesced dwords
        __builtin_nontemporal_store(g0, &out[(size_t)(b0 + 0) * OUT_DIM + o]);
        __builtin_nontemporal_store(g1, &out[(size_t)(b0 + 1) * OUT_DIM + o]);
        __builtin_nontemporal_store(g2, &out[(size_t)(b0 + 2) * OUT_DIM + o]);
        __builtin_nontemporal_store(g3, &out[(size_t)(b0 + 3) * OUT_DIM + o]);
    }
}

extern "C" void kernel_launch(void* const* d_in, const int* in_sizes, int n_in,
                              void* d_out, int out_size, void* d_ws, size_t ws_size,
                              hipStream_t stream) {
    const float* x     = (const float*)d_in[0];
    const int*   idx   = (const int*)  d_in[1];
    const float* w     = (const float*)d_in[2];
    const float* theta = (const float*)d_in[3];
    const float* s_raw = (const float*)d_in[4];
    float* out = (float*)d_out;

    dim3 grid(2 * NTILES);   // 512 blocks: pair (T, T+256) shares XCD + batch tile
    dim3 block(NT);          // 1024 threads; 2 blocks/CU -> 32 waves/CU
    WeightedThresholdGate_53085795778563_kernel<<<grid, block, 0, stream>>>(
        x, idx, w, theta, s_raw, out);
}